// Round 2
// baseline (1235.260 us; speedup 1.0000x reference)
//
#include <hip/hip_runtime.h>

// RWKV-5 WKV, f32, chunked parallel scan over T.
// B=4, T=4096, H=32, S=64.  State kept scaled: X = s_raw*SCALE.
//   X' = td*X + k*(v*SCALE);  wkv[d] = sum_s r[s]*(tf[s]*k[s]*vs[d] + X[s,d])
// Linear diagonal recurrence => chunk decomposition:
//   X_end(chunk) = td^L * X_start + P(chunk),  P = zero-init partial.
// pass1: P(c) for all chunks (parallel).  pass2: propagate Xin(c) (cheap,
// sequential over C only).  pass3: per-chunk scan with outputs from Xin(c).

namespace {
constexpr int cB = 4, cT = 4096, cH = 32, cS = 64;
constexpr int cTS = cH * cS;          // 2048 floats per timestep
constexpr float cScale = 1.0f / 128.0f;
constexpr int cC = 8;                 // chunks per (b,h)
constexpr int cL = cT / cC;           // 512 steps per chunk
constexpr int cBH = cB * cH;          // 128
constexpr int cGrp = cL / 4;          // 128 groups of 4 timesteps
}

typedef float v2f __attribute__((ext_vector_type(2)));

// -------- pass1: per-chunk partial state, zero-init scan (no r, no out) ----
__global__ __launch_bounds__(64)
void rwkv5_pass1(const float* __restrict__ K, const float* __restrict__ V,
                 const float* __restrict__ TD, float* __restrict__ P) {
    const int idx = blockIdx.x;
    const int dg  = idx >> 10;        // 0..7
    const int u   = idx & 1023;       // bh*cC + c ; XCD = u%8 groups dg-peers
    const int bh  = u >> 3;
    const int c   = u & 7;
    const int b = bh >> 5, h = bh & 31;
    const int lane = threadIdx.x;
    const int dsub = lane & 7, d = dg * 8 + dsub;
    const int sb   = (lane >> 3) * 8;

    v2f td2[4];
#pragma unroll
    for (int j = 0; j < 4; ++j)
        td2[j] = v2f{TD[h * cS + sb + 2 * j], TD[h * cS + sb + 2 * j + 1]};

    v2f s2[4] = {v2f{0.f, 0.f}, v2f{0.f, 0.f}, v2f{0.f, 0.f}, v2f{0.f, 0.f}};

    const size_t tb = (size_t)b * cT * cTS + (size_t)c * cL * cTS;
    const float* kp = K + tb + h * cS + sb;
    const float* vp = V + tb + h * cS + d;

    v2f  kA[4][4], kB[4][4];
    float vA[4], vB[4];

    auto loadG = [&](int g, v2f (&kb)[4][4], float (&vb)[4]) {
        const int gg = (g < cGrp) ? g : (cGrp - 1);
        const size_t off = (size_t)gg * 4 * cTS;
#pragma unroll
        for (int i = 0; i < 4; ++i) {
            const float* kk = kp + off + (size_t)i * cTS;
            *reinterpret_cast<float4*>(&kb[i][0]) =
                *reinterpret_cast<const float4*>(kk);
            *reinterpret_cast<float4*>(&kb[i][2]) =
                *reinterpret_cast<const float4*>(kk + 4);
            vb[i] = vp[off + (size_t)i * cTS];
        }
    };
    auto compG = [&](v2f (&kb)[4][4], float (&vb)[4]) {
#pragma unroll
        for (int i = 0; i < 4; ++i) {
            const float vs = vb[i] * cScale;
            const v2f vs2 = {vs, vs};
#pragma unroll
            for (int j = 0; j < 4; ++j) {
                v2f kv = kb[i][j] * vs2;
                s2[j] = td2[j] * s2[j] + kv;
            }
        }
    };

    loadG(0, kA, vA);
    for (int g = 0; g < cGrp; g += 2) {
        loadG(g + 1, kB, vB);
        compG(kA, vA);
        loadG(g + 2, kA, vA);
        compG(kB, vB);
    }

    float* pp = P + ((size_t)u * cS + sb) * cS + d;
#pragma unroll
    for (int j = 0; j < 4; ++j) {
        pp[(size_t)(2 * j) * cS]     = s2[j].x;
        pp[(size_t)(2 * j + 1) * cS] = s2[j].y;
    }
}

// -------- pass2: propagate chunk-entry states, overwrite P with Xin --------
__global__ __launch_bounds__(256)
void rwkv5_pass2(const float* __restrict__ S2in, const float* __restrict__ TD,
                 float* __restrict__ P) {
    const int bh = blockIdx.x;
    const int h  = bh & 31;
    const int t  = threadIdx.x;
    const int s  = t >> 2;                 // 4 threads per s-row
    const int db = (t & 3) * 16;           // 16 consecutive d per thread

    const float td = TD[h * cS + s];
    float tdL = 1.0f, pw = td;
    int e = cL;
    while (e) { if (e & 1) tdL *= pw; pw *= pw; e >>= 1; }

    float4 x[4];
    const float* s0 = S2in + ((size_t)bh * cS + s) * cS + db;
#pragma unroll
    for (int i = 0; i < 4; ++i) {
        x[i] = *reinterpret_cast<const float4*>(s0 + i * 4);
        x[i].x *= cScale; x[i].y *= cScale; x[i].z *= cScale; x[i].w *= cScale;
    }

    for (int c = 0; c < cC; ++c) {
        float* base = P + (((size_t)bh * cC + c) * cS + s) * cS + db;
        float4 pr[4];
#pragma unroll
        for (int i = 0; i < 4; ++i)
            pr[i] = *reinterpret_cast<const float4*>(base + i * 4);
        // write Xin(c) over P(c)
#pragma unroll
        for (int i = 0; i < 4; ++i)
            *reinterpret_cast<float4*>(base + i * 4) = x[i];
        // x = td^L * x + P(c)
#pragma unroll
        for (int i = 0; i < 4; ++i) {
            x[i].x = fmaf(tdL, x[i].x, pr[i].x);
            x[i].y = fmaf(tdL, x[i].y, pr[i].y);
            x[i].z = fmaf(tdL, x[i].z, pr[i].z);
            x[i].w = fmaf(tdL, x[i].w, pr[i].w);
        }
    }
}

// -------- pass3: per-chunk scan with outputs, seeded from Xin --------------
__global__ __launch_bounds__(64)
void rwkv5_pass3(const float* __restrict__ K, const float* __restrict__ V,
                 const float* __restrict__ R, const float* __restrict__ TF,
                 const float* __restrict__ TD, const float* __restrict__ Xin,
                 float* __restrict__ Out) {
    const int idx = blockIdx.x;
    const int dg  = idx >> 10;
    const int u   = idx & 1023;
    const int bh  = u >> 3;
    const int c   = u & 7;
    const int b = bh >> 5, h = bh & 31;
    const int lane = threadIdx.x;
    const int dsub = lane & 7, d = dg * 8 + dsub;
    const int sb   = (lane >> 3) * 8;

    v2f tf2[4], td2[4];
#pragma unroll
    for (int j = 0; j < 4; ++j) {
        tf2[j] = v2f{TF[h * cS + sb + 2 * j], TF[h * cS + sb + 2 * j + 1]};
        td2[j] = v2f{TD[h * cS + sb + 2 * j], TD[h * cS + sb + 2 * j + 1]};
    }

    v2f s2[4];
    const float* xp = Xin + ((size_t)u * cS + sb) * cS + d;
#pragma unroll
    for (int j = 0; j < 4; ++j) {
        s2[j].x = xp[(size_t)(2 * j) * cS];
        s2[j].y = xp[(size_t)(2 * j + 1) * cS];
    }

    const size_t tb = (size_t)b * cT * cTS + (size_t)c * cL * cTS;
    const float* kp = K + tb + h * cS + sb;
    const float* rp = R + tb + h * cS + sb;
    const float* vp = V + tb + h * cS + d;
    float*       op = Out + tb + h * cS + d;

    v2f  kA[4][4], rA[4][4], kB[4][4], rB[4][4];
    float vA[4], vB[4];

    auto loadG = [&](int g, v2f (&kb)[4][4], v2f (&rb)[4][4], float (&vb)[4]) {
        const int gg = (g < cGrp) ? g : (cGrp - 1);
        const size_t off = (size_t)gg * 4 * cTS;
#pragma unroll
        for (int i = 0; i < 4; ++i) {
            const float* kk = kp + off + (size_t)i * cTS;
            const float* rr = rp + off + (size_t)i * cTS;
            *reinterpret_cast<float4*>(&kb[i][0]) =
                *reinterpret_cast<const float4*>(kk);
            *reinterpret_cast<float4*>(&kb[i][2]) =
                *reinterpret_cast<const float4*>(kk + 4);
            *reinterpret_cast<float4*>(&rb[i][0]) =
                *reinterpret_cast<const float4*>(rr);
            *reinterpret_cast<float4*>(&rb[i][2]) =
                *reinterpret_cast<const float4*>(rr + 4);
            vb[i] = vp[off + (size_t)i * cTS];
        }
    };

    auto compG = [&](int g, v2f (&kb)[4][4], v2f (&rb)[4][4], float (&vb)[4]) {
        float acc[4];
#pragma unroll
        for (int i = 0; i < 4; ++i) {
            const float vs = vb[i] * cScale;
            const v2f vs2 = {vs, vs};
            v2f a2 = {0.f, 0.f};
#pragma unroll
            for (int j = 0; j < 4; ++j) {
                v2f kv  = kb[i][j] * vs2;
                v2f tmp = tf2[j] * kv + s2[j];
                a2 = rb[i][j] * tmp + a2;
                s2[j] = td2[j] * s2[j] + kv;
            }
            acc[i] = a2.x + a2.y;
        }
#pragma unroll
        for (int i = 0; i < 4; ++i) acc[i] += __shfl_xor(acc[i], 8, 64);
#pragma unroll
        for (int i = 0; i < 4; ++i) acc[i] += __shfl_xor(acc[i], 16, 64);
#pragma unroll
        for (int i = 0; i < 4; ++i) acc[i] += __shfl_xor(acc[i], 32, 64);
        if (sb == 0) {
#pragma unroll
            for (int i = 0; i < 4; ++i)
                op[(size_t)(g * 4 + i) * cTS] = acc[i];
        }
    };

    loadG(0, kA, rA, vA);
    for (int g = 0; g < cGrp; g += 2) {
        loadG(g + 1, kB, rB, vB);
        compG(g, kA, rA, vA);
        loadG(g + 2, kA, rA, vA);
        compG(g + 1, kB, rB, vB);
    }

    if (c == cC - 1) {
        float* o2 = Out + (size_t)cB * cT * cTS + (size_t)bh * cS * cS
                    + (size_t)sb * cS + d;
#pragma unroll
        for (int j = 0; j < 4; ++j) {
            o2[(size_t)(2 * j) * cS]     = s2[j].x * 128.0f;
            o2[(size_t)(2 * j + 1) * cS] = s2[j].y * 128.0f;
        }
    }
}

extern "C" void kernel_launch(void* const* d_in, const int* in_sizes, int n_in,
                              void* d_out, int out_size, void* d_ws,
                              size_t ws_size, hipStream_t stream) {
    const float* K    = (const float*)d_in[0];
    const float* V    = (const float*)d_in[1];
    const float* R    = (const float*)d_in[2];
    const float* S2in = (const float*)d_in[3];
    const float* TF   = (const float*)d_in[4];
    const float* TD   = (const float*)d_in[5];
    float* OutP = (float*)d_out;
    float* P    = (float*)d_ws;   // cBH*cC*cS*cS floats = 16.8 MB
    (void)in_sizes; (void)n_in; (void)ws_size; (void)out_size;

    rwkv5_pass1<<<dim3(cBH * cC * 8), dim3(64), 0, stream>>>(K, V, TD, P);
    rwkv5_pass2<<<dim3(cBH), dim3(256), 0, stream>>>(S2in, TD, P);
    rwkv5_pass3<<<dim3(cBH * cC * 8), dim3(64), 0, stream>>>(K, V, R, TF, TD,
                                                             P, OutP);
}

// Round 3
// 483.374 us; speedup vs baseline: 2.5555x; 2.5555x over previous
//
#include <hip/hip_runtime.h>

// RWKV-5 WKV, f32, chunked parallel scan + LDS-staged k/r/v.
// B=4, T=4096, H=32, S=64.  State scaled: X = s_raw*SCALE.
//   X' = td*X + k*(v*SCALE);  wkv[d] = sum_s r[s]*(tf[s]*k[s]*vs[d] + X[s,d])
// pass1: per-chunk partial states (zero-init scan, k/v only).
// pass2: propagate chunk-entry states Xin (tiny).
// pass3: per-chunk scan with outputs, seeded from Xin.
// pass1/pass3: one 512-thread block (8 waves) per (bh, chunk); wave w owns
// d-group w. k/r/v rows staged ONCE per block into triple-buffered LDS via
// global_load_lds; raw s_barrier + counted vmcnt keeps prefetch in flight.

namespace {
constexpr int cB = 4, cT = 4096, cH = 32, cS = 64;
constexpr int cTS = cH * cS;          // 2048 floats per timestep
constexpr float cScale = 1.0f / 128.0f;
constexpr int cC = 8;                 // chunks per (b,h)
constexpr int cL = cT / cC;           // 512 steps per chunk
constexpr int cBH = cB * cH;          // 128
constexpr int cG = 8;                 // timesteps per staged group
constexpr int cNG = cL / cG;          // 64 groups per chunk
}

typedef float v2f __attribute__((ext_vector_type(2)));

__device__ __forceinline__ void gl16(const float* g, float* lds) {
    __builtin_amdgcn_global_load_lds(
        (const __attribute__((address_space(1))) unsigned int*)g,
        (__attribute__((address_space(3))) unsigned int*)lds, 16, 0, 0);
}
#define BAR_A() asm volatile("s_waitcnt lgkmcnt(0)\ns_barrier" ::: "memory")
#define BAR_B() asm volatile("s_barrier" ::: "memory")
#define VMW(N)  asm volatile("s_waitcnt vmcnt(" #N ")" ::: "memory")

// ---------------- pass1: partial chunk states ------------------------------
__global__ __launch_bounds__(512)
void rwkv5_pass1(const float* __restrict__ K, const float* __restrict__ V,
                 const float* __restrict__ TD, float* __restrict__ P) {
    __shared__ float kS[3][cG][cS], vS[3][cG][cS];
    const int u  = blockIdx.x;            // bh*cC + c
    const int bh = u >> 3, c = u & 7;
    const int b = bh >> 5, h = bh & 31;
    const int tid = threadIdx.x, wid = tid >> 6, lane = tid & 63;
    const int dsub = lane & 7, d = wid * 8 + dsub;
    const int sb = (lane >> 3) * 8;

    v2f td2[4];
#pragma unroll
    for (int j = 0; j < 4; ++j)
        td2[j] = v2f{TD[h*cS + sb + 2*j], TD[h*cS + sb + 2*j + 1]};

    v2f s2[4] = {v2f{0.f,0.f}, v2f{0.f,0.f}, v2f{0.f,0.f}, v2f{0.f,0.f}};

    const size_t tb = (size_t)b*cT*cTS + (size_t)c*cL*cTS;
    const float* kBase = K + tb + h*cS;
    const float* vBase = V + tb + h*cS;
    const int half = wid & 1;
    const float* sBase = (wid < 2) ? kBase : vBase;

    auto stage = [&](int g, int bi) {
        if (wid < 4) {                       // waves 0,1: k halves; 2,3: v halves
            const int gg = (g < cNG) ? g : cNG - 1;
            const float* gp = sBase + ((size_t)gg*cG + half*4 + (lane>>4))*cTS
                              + (lane & 15)*4;
            float* lp = (wid < 2) ? &kS[bi][half*4][0] : &vS[bi][half*4][0];
            gl16(gp, lp);
        }
    };
    auto compute = [&](int bi) {
#pragma unroll
        for (int t = 0; t < cG; ++t) {
            const float vs = vS[bi][t][d] * cScale;
            const v2f vs2 = {vs, vs};
            const float4 kx = *(const float4*)&kS[bi][t][sb];
            const float4 ky = *(const float4*)&kS[bi][t][sb+4];
            const v2f kk[4] = {{kx.x,kx.y},{kx.z,kx.w},{ky.x,ky.y},{ky.z,ky.w}};
#pragma unroll
            for (int j = 0; j < 4; ++j) {
                v2f kv = kk[j] * vs2;
                s2[j] = td2[j] * s2[j] + kv;
            }
        }
    };

    stage(0, 0);
    stage(1, 1);
    stage(2, 2);          // g=0 peel
    VMW(2);
    BAR_B();
    compute(0);
    int cur = 0, nb = 0;  // nb = (g+2)%3 starting at g=1
    for (int g = 1; g < cNG; ++g) {
        BAR_A();
        stage(g + 2, nb);
        VMW(2);
        BAR_B();
        cur = (cur == 2) ? 0 : cur + 1;
        compute(cur);
        nb = (nb == 2) ? 0 : nb + 1;
    }

    float* pp = P + ((size_t)u*cS + sb)*cS + d;
#pragma unroll
    for (int j = 0; j < 4; ++j) {
        pp[(size_t)(2*j)*cS]   = s2[j].x;
        pp[(size_t)(2*j+1)*cS] = s2[j].y;
    }
}

// ---------------- pass2: propagate chunk-entry states ----------------------
__global__ __launch_bounds__(256)
void rwkv5_pass2(const float* __restrict__ S2in, const float* __restrict__ TD,
                 float* __restrict__ P) {
    const int bh = blockIdx.x;
    const int h  = bh & 31;
    const int t  = threadIdx.x;
    const int s  = t >> 2;
    const int db = (t & 3) * 16;

    const float td = TD[h * cS + s];
    float tdL = 1.0f, pw = td;
    int e = cL;
    while (e) { if (e & 1) tdL *= pw; pw *= pw; e >>= 1; }

    float4 x[4];
    const float* s0 = S2in + ((size_t)bh * cS + s) * cS + db;
#pragma unroll
    for (int i = 0; i < 4; ++i) {
        x[i] = *reinterpret_cast<const float4*>(s0 + i * 4);
        x[i].x *= cScale; x[i].y *= cScale; x[i].z *= cScale; x[i].w *= cScale;
    }
    for (int c = 0; c < cC; ++c) {
        float* base = P + (((size_t)bh * cC + c) * cS + s) * cS + db;
        float4 pr[4];
#pragma unroll
        for (int i = 0; i < 4; ++i)
            pr[i] = *reinterpret_cast<const float4*>(base + i * 4);
#pragma unroll
        for (int i = 0; i < 4; ++i)
            *reinterpret_cast<float4*>(base + i * 4) = x[i];
#pragma unroll
        for (int i = 0; i < 4; ++i) {
            x[i].x = fmaf(tdL, x[i].x, pr[i].x);
            x[i].y = fmaf(tdL, x[i].y, pr[i].y);
            x[i].z = fmaf(tdL, x[i].z, pr[i].z);
            x[i].w = fmaf(tdL, x[i].w, pr[i].w);
        }
    }
}

// ---------------- pass3: per-chunk scan with outputs -----------------------
__global__ __launch_bounds__(512)
void rwkv5_pass3(const float* __restrict__ K, const float* __restrict__ V,
                 const float* __restrict__ R, const float* __restrict__ TF,
                 const float* __restrict__ TD, const float* __restrict__ Xin,
                 float* __restrict__ Out) {
    __shared__ float kS[3][cG][cS], rS[3][cG][cS], vS[3][cG][cS];
    const int u  = blockIdx.x;            // bh*cC + c
    const int bh = u >> 3, c = u & 7;
    const int b = bh >> 5, h = bh & 31;
    const int tid = threadIdx.x, wid = tid >> 6, lane = tid & 63;
    const int dsub = lane & 7, d = wid * 8 + dsub;
    const int sg = lane >> 3, sb = sg * 8;

    v2f tf2[4], td2[4];
#pragma unroll
    for (int j = 0; j < 4; ++j) {
        tf2[j] = v2f{TF[h*cS + sb + 2*j], TF[h*cS + sb + 2*j + 1]};
        td2[j] = v2f{TD[h*cS + sb + 2*j], TD[h*cS + sb + 2*j + 1]};
    }

    v2f s2[4];
    const float* xp = Xin + ((size_t)u*cS + sb)*cS + d;
#pragma unroll
    for (int j = 0; j < 4; ++j) {
        s2[j].x = xp[(size_t)(2*j)*cS];
        s2[j].y = xp[(size_t)(2*j+1)*cS];
    }

    const size_t tb = (size_t)b*cT*cTS + (size_t)c*cL*cTS;
    const float* kBase = K + tb + h*cS;
    const float* rBase = R + tb + h*cS;
    const float* vBase = V + tb + h*cS;
    const int kind = wid >> 1, half = wid & 1;
    const float* sBase = (kind == 0) ? kBase : (kind == 1) ? rBase : vBase;
    float* outp = Out + tb + (size_t)sg*cTS + h*cS + d;

    auto stage = [&](int g, int bi) {
        if (wid < 6) {                    // 0,1:k  2,3:r  4,5:v
            const int gg = (g < cNG) ? g : cNG - 1;
            const float* gp = sBase + ((size_t)gg*cG + half*4 + (lane>>4))*cTS
                              + (lane & 15)*4;
            float* lp = (kind == 0) ? &kS[bi][half*4][0]
                      : (kind == 1) ? &rS[bi][half*4][0]
                                    : &vS[bi][half*4][0];
            gl16(gp, lp);
        }
    };
    auto compute = [&](int g, int bi) {
        float acc[cG];
#pragma unroll
        for (int t = 0; t < cG; ++t) {
            const float vs = vS[bi][t][d] * cScale;
            const v2f vs2 = {vs, vs};
            const float4 kx = *(const float4*)&kS[bi][t][sb];
            const float4 ky = *(const float4*)&kS[bi][t][sb+4];
            const float4 rx = *(const float4*)&rS[bi][t][sb];
            const float4 ry = *(const float4*)&rS[bi][t][sb+4];
            const v2f kk[4] = {{kx.x,kx.y},{kx.z,kx.w},{ky.x,ky.y},{ky.z,ky.w}};
            const v2f rr[4] = {{rx.x,rx.y},{rx.z,rx.w},{ry.x,ry.y},{ry.z,ry.w}};
            v2f a2 = {0.f, 0.f};
#pragma unroll
            for (int j = 0; j < 4; ++j) {
                v2f kv  = kk[j] * vs2;
                v2f tmp = tf2[j] * kv + s2[j];
                a2 = rr[j] * tmp + a2;
                s2[j] = td2[j] * s2[j] + kv;
            }
            acc[t] = a2.x + a2.y;
        }
        // reduce over the 8 s-groups (lane bits 3,4,5)
#pragma unroll
        for (int t = 0; t < cG; ++t) acc[t] += __shfl_xor(acc[t], 8, 64);
#pragma unroll
        for (int t = 0; t < cG; ++t) acc[t] += __shfl_xor(acc[t], 16, 64);
#pragma unroll
        for (int t = 0; t < cG; ++t) acc[t] += __shfl_xor(acc[t], 32, 64);
        // lane (sg,dsub) stores timestep g*8+sg, dim d: one store per lane
        const float a_ = (sg & 1) ? acc[1] : acc[0];
        const float b_ = (sg & 1) ? acc[3] : acc[2];
        const float c_ = (sg & 1) ? acc[5] : acc[4];
        const float d_ = (sg & 1) ? acc[7] : acc[6];
        const float e_ = (sg & 2) ? b_ : a_;
        const float f_ = (sg & 2) ? d_ : c_;
        const float o_ = (sg & 4) ? f_ : e_;
        outp[(size_t)g*cG*cTS] = o_;
    };

    stage(0, 0);
    stage(1, 1);
    stage(2, 2);          // g=0 peel
    VMW(2);
    BAR_B();
    compute(0, 0);
    int cur = 0, nb = 0;
    for (int g = 1; g < cNG; ++g) {
        BAR_A();
        stage(g + 2, nb);
        VMW(3);
        BAR_B();
        cur = (cur == 2) ? 0 : cur + 1;
        compute(g, cur);
        nb = (nb == 2) ? 0 : nb + 1;
    }

    if (c == cC - 1) {
        float* o2 = Out + (size_t)cB*cT*cTS + (size_t)bh*cS*cS;
#pragma unroll
        for (int j = 0; j < 4; ++j) {
            o2[(size_t)(sb + 2*j)*cS + d]   = s2[j].x * 128.0f;
            o2[(size_t)(sb + 2*j+1)*cS + d] = s2[j].y * 128.0f;
        }
    }
}

extern "C" void kernel_launch(void* const* d_in, const int* in_sizes, int n_in,
                              void* d_out, int out_size, void* d_ws,
                              size_t ws_size, hipStream_t stream) {
    const float* K    = (const float*)d_in[0];
    const float* V    = (const float*)d_in[1];
    const float* R    = (const float*)d_in[2];
    const float* S2in = (const float*)d_in[3];
    const float* TF   = (const float*)d_in[4];
    const float* TD   = (const float*)d_in[5];
    float* OutP = (float*)d_out;
    float* P    = (float*)d_ws;   // cBH*cC*cS*cS floats = 16.8 MB
    (void)in_sizes; (void)n_in; (void)ws_size; (void)out_size;

    rwkv5_pass1<<<dim3(cBH * cC), dim3(512), 0, stream>>>(K, V, TD, P);
    rwkv5_pass2<<<dim3(cBH), dim3(256), 0, stream>>>(S2in, TD, P);
    rwkv5_pass3<<<dim3(cBH * cC), dim3(512), 0, stream>>>(K, V, R, TF, TD,
                                                          P, OutP);
}